// Round 3
// baseline (1234.880 us; speedup 1.0000x reference)
//
#include <hip/hip_runtime.h>

#define H  64
#define G4 256   // 4*H

// fast sigmoid/tanh: v_exp_f32 + v_rcp_f32. Safe at +-inf:
//   x->-inf: exp(-x)=inf -> rcp(inf)=0 ; x->+inf: exp(-x)=0 -> rcp(1)=1
__device__ __forceinline__ float sigm(float x) {
    return __builtin_amdgcn_rcpf(1.0f + __expf(-x));
}
__device__ __forceinline__ float tanh_s(float x) {
    return fmaf(2.0f, sigm(2.0f * x), -1.0f);
}

__device__ __forceinline__ float bcast(float v, int lane) {
    return __int_as_float(__builtin_amdgcn_readlane(__float_as_int(v), lane));
}

// X-macro over 0..63 (64 named scalars -> no array, no SROA/scratch hazard)
#define R64(M) \
  M(0) M(1) M(2) M(3) M(4) M(5) M(6) M(7) M(8) M(9) M(10) M(11) M(12) M(13) M(14) M(15) \
  M(16) M(17) M(18) M(19) M(20) M(21) M(22) M(23) M(24) M(25) M(26) M(27) M(28) M(29) M(30) M(31) \
  M(32) M(33) M(34) M(35) M(36) M(37) M(38) M(39) M(40) M(41) M(42) M(43) M(44) M(45) M(46) M(47) \
  M(48) M(49) M(50) M(51) M(52) M(53) M(54) M(55) M(56) M(57) M(58) M(59) M(60) M(61) M(62) M(63)

// P[v][g] = sum_h table[v][h] * w_ih[g][h] + b_ih[g] + b_hh[g], table[0] = 0
// blockIdx.y = 0 -> forward params, 1 -> backward params.
__global__ __launch_bounds__(256)
void proj_kernel(const float* __restrict__ emb,
                 const float* __restrict__ w_ih_f,
                 const float* __restrict__ b_ih_f,
                 const float* __restrict__ b_hh_f,
                 const float* __restrict__ w_ih_b,
                 const float* __restrict__ b_ih_b,
                 const float* __restrict__ b_hh_b,
                 float* __restrict__ Pf,
                 float* __restrict__ Pb,
                 int V)
{
    const int j  = threadIdx.x;       // output gate index 0..255
    const int v0 = blockIdx.x * 8;
    const bool bwd = (blockIdx.y != 0);

    const float* __restrict__ w_ih = bwd ? w_ih_b : w_ih_f;
    const float* __restrict__ b_ih = bwd ? b_ih_b : b_ih_f;
    const float* __restrict__ b_hh = bwd ? b_hh_b : b_hh_f;
    float* __restrict__ P          = bwd ? Pb     : Pf;

    __shared__ float es[8][H];
    // cooperative load of 8 embedding rows (512 floats, 2 per thread)
    {
        int idx = j;
        #pragma unroll
        for (int rep = 0; rep < 2; ++rep, idx += 256) {
            int r = idx >> 6, col = idx & 63;
            int v = v0 + r;
            float val = 0.0f;
            if (v < V && v != 0) val = emb[v * H + col];   // padding_idx=0
            es[r][col] = val;
        }
    }

    float w[H];
    const float4* w4 = reinterpret_cast<const float4*>(w_ih + j * H);
    #pragma unroll
    for (int i = 0; i < 16; ++i) {
        float4 t = w4[i];
        w[4*i] = t.x; w[4*i+1] = t.y; w[4*i+2] = t.z; w[4*i+3] = t.w;
    }
    float bias = b_ih[j] + b_hh[j];
    __syncthreads();

    #pragma unroll
    for (int r = 0; r < 8; ++r) {
        int v = v0 + r;
        if (v >= V) break;
        float a0 = 0, a1 = 0, a2 = 0, a3 = 0;
        #pragma unroll
        for (int k = 0; k < H; k += 4) {
            a0 = fmaf(es[r][k+0], w[k+0], a0);
            a1 = fmaf(es[r][k+1], w[k+1], a1);
            a2 = fmaf(es[r][k+2], w[k+2], a2);
            a3 = fmaf(es[r][k+3], w[k+3], a3);
        }
        P[v * G4 + j] = bias + ((a0 + a1) + (a2 + a3));
    }
}

// One block per batch element. 4 waves; wave w owns gate w (rows 64w..64w+63
// of w_hh). The 64 recurrent weights per thread are parked in AGPRs via
// explicit v_accvgpr_write/read (R1/R2 evidence: the allocator refuses to
// keep them in VGPRs -- VGPR_Count=40, ~1117 cyc/step == 64KB/step L2
// refetch). AGPR residency is deterministic: the write asm defines an
// "a"-class value, the volatile read in the loop cannot be hoisted.
__global__ __launch_bounds__(256, 1)
void lstm_kernel(const int* __restrict__ x,      // [B,T]
                 const float* __restrict__ Pf,   // [V,4H]
                 const float* __restrict__ Pb,   // [V,4H]
                 const float* __restrict__ w_hh, // [4H,H] (forward)
                 const float* __restrict__ w_fc, // [12,2H]
                 const float* __restrict__ b_fc, // [12]
                 float* __restrict__ out,        // [B,12]
                 int T)
{
    const int b    = blockIdx.x;
    const int j    = threadIdx.x;   // gate-output row 0..255
    const int lane = j & 63;
    const int gate = j >> 6;        // == wave id: 0=i 1=f 2=g 3=o

    // load per-thread recurrent weight row, then park all 64 in AGPRs
    float lw[H];
    const float4* w4 = reinterpret_cast<const float4*>(w_hh + j * H);
    #pragma unroll
    for (int i = 0; i < 16; ++i) {
        float4 t = w4[i];
        lw[4*i] = t.x; lw[4*i+1] = t.y; lw[4*i+2] = t.z; lw[4*i+3] = t.w;
    }

    #define WDECL(i) float wa_##i;
    R64(WDECL)
    #undef WDECL
    #define WWRITE(i) asm volatile("v_accvgpr_write_b32 %0, %1" : "=a"(wa_##i) : "v"(lw[i]));
    R64(WWRITE)
    #undef WWRITE

    // branchless activation: act = Aa * sigm(ms*s) + Ba
    const float ms = (gate == 2) ? 2.0f : 1.0f;
    const float Aa = (gate == 2) ? 2.0f : 1.0f;
    const float Ba = (gate == 2) ? -1.0f : 0.0f;

    __shared__ float g_s[2][G4];
    __shared__ float hf_s[H];
    __shared__ float hb_s[H];

    const int* __restrict__ xrow = x + (long)b * T;

    float h = 0.0f;   // lane's h value (replicated across all 4 waves)
    float c = 0.0f;

    int   tok_next = (T > 1) ? xrow[1] : 0;
    float p_cur    = Pf[xrow[0] * G4 + j];

    for (int t = 0; t < T; ++t) {
        // prefetch next timestep's projected input (L2-resident gather)
        float p_next = 0.0f;
        if (t + 1 < T) p_next = Pf[tok_next * G4 + j];
        int tok_next2 = (t + 2 < T) ? xrow[t + 2] : 0;

        // s = p_cur + sum_k w[k] * h[k]
        // weights stream out of AGPRs; h broadcast via v_readlane (SGPR)
        float acc[4] = {0.0f, 0.0f, 0.0f, 0.0f};
        #define WSTEP(i) { float t_;                                          \
            asm volatile("v_accvgpr_read_b32 %0, %1" : "=v"(t_) : "a"(wa_##i)); \
            acc[(i) & 3] = fmaf(t_, bcast(h, (i)), acc[(i) & 3]); }
        R64(WSTEP)
        #undef WSTEP

        float s   = p_cur + ((acc[0] + acc[1]) + (acc[2] + acc[3]));
        float act = fmaf(Aa, sigm(ms * s), Ba);

        const int ph = t & 1;
        g_s[ph][j] = act;
        __syncthreads();   // the single per-step barrier (gate exchange)

        float gi = g_s[ph][lane];
        float gf = g_s[ph][H   + lane];
        float gg = g_s[ph][2*H + lane];
        float go = g_s[ph][3*H + lane];
        c = fmaf(gf, c, gi * gg);
        h = go * tanh_s(c);

        p_cur    = p_next;
        tok_next = tok_next2;
    }

    __syncthreads();   // protect g_s[0] reuse below

    // backward LSTM: exactly one step (hs_b[0]) with zero initial state
    {
        int   tokL = xrow[T - 1];
        float gb   = Pb[tokL * G4 + j];
        g_s[0][j]  = fmaf(Aa, sigm(ms * gb), Ba);
    }
    if (gate == 0) hf_s[lane] = h;
    __syncthreads();

    if (j < H) {
        float i_ = g_s[0][j];
        float gg = g_s[0][2*H + j];
        float go = g_s[0][3*H + j];
        float cb = i_ * gg;               // f*c0 = 0
        hb_s[j] = go * tanh_s(cb);
    }
    __syncthreads();

    // final FC: y[b, j] = b_fc[j] + [h_f | h_b] . w_fc[j]
    if (j < 12) {
        float acc = b_fc[j];
        const float* wf = w_fc + j * (2 * H);
        #pragma unroll
        for (int k = 0; k < H; ++k) acc = fmaf(hf_s[k], wf[k], acc);
        #pragma unroll
        for (int k = 0; k < H; ++k) acc = fmaf(hb_s[k], wf[H + k], acc);
        out[b * 12 + j] = acc;
    }
}

extern "C" void kernel_launch(void* const* d_in, const int* in_sizes, int n_in,
                              void* d_out, int out_size, void* d_ws, size_t ws_size,
                              hipStream_t stream)
{
    const int*   x      = (const int*)  d_in[0];
    const float* emb    = (const float*)d_in[1];
    const float* w_ih_f = (const float*)d_in[2];
    const float* w_hh_f = (const float*)d_in[3];
    const float* b_ih_f = (const float*)d_in[4];
    const float* b_hh_f = (const float*)d_in[5];
    const float* w_ih_b = (const float*)d_in[6];
    // d_in[7] = w_hh_b (unused: backward runs exactly one step from zero state)
    const float* b_ih_b = (const float*)d_in[8];
    const float* b_hh_b = (const float*)d_in[9];
    const float* w_fc   = (const float*)d_in[10];
    const float* b_fc   = (const float*)d_in[11];
    float* out = (float*)d_out;

    const int B = out_size / 12;
    const int T = in_sizes[0] / B;
    const int V = in_sizes[1] / H;

    float* Pf = (float*)d_ws;                   // [V,4H]
    float* Pb = Pf + (size_t)V * G4;            // [V,4H]  (4 MB total)

    int pblocks = (V + 7) / 8;
    dim3 pgrid(pblocks, 2);
    proj_kernel<<<pgrid, 256, 0, stream>>>(emb, w_ih_f, b_ih_f, b_hh_f,
                                           w_ih_b, b_ih_b, b_hh_b, Pf, Pb, V);
    lstm_kernel<<<B, 256, 0, stream>>>(x, Pf, Pb, w_hh_f, w_fc, b_fc, out, T);
}

// Round 4
// 973.983 us; speedup vs baseline: 1.2679x; 1.2679x over previous
//
#include <hip/hip_runtime.h>

#define H  64
#define G4 256   // 4*H

// fast sigmoid/tanh: v_exp_f32 + v_rcp_f32. Safe at +-inf:
//   x->-inf: exp(-x)=inf -> rcp(inf)=0 ; x->+inf: exp(-x)=0 -> rcp(1)=1
__device__ __forceinline__ float sigm(float x) {
    return __builtin_amdgcn_rcpf(1.0f + __expf(-x));
}
__device__ __forceinline__ float tanh_s(float x) {
    return fmaf(2.0f, sigm(2.0f * x), -1.0f);
}

__device__ __forceinline__ float bcast(float v, int lane) {
    return __int_as_float(__builtin_amdgcn_readlane(__float_as_int(v), lane));
}

// P[v][g] = sum_h table[v][h] * w_ih[g][h] + b_ih[g] + b_hh[g], table[0] = 0
// blockIdx.y = 0 -> forward params, 1 -> backward params.
__global__ __launch_bounds__(256)
void proj_kernel(const float* __restrict__ emb,
                 const float* __restrict__ w_ih_f,
                 const float* __restrict__ b_ih_f,
                 const float* __restrict__ b_hh_f,
                 const float* __restrict__ w_ih_b,
                 const float* __restrict__ b_ih_b,
                 const float* __restrict__ b_hh_b,
                 float* __restrict__ Pf,
                 float* __restrict__ Pb,
                 int V)
{
    const int j  = threadIdx.x;       // output gate index 0..255
    const int v0 = blockIdx.x * 8;
    const bool bwd = (blockIdx.y != 0);

    const float* __restrict__ w_ih = bwd ? w_ih_b : w_ih_f;
    const float* __restrict__ b_ih = bwd ? b_ih_b : b_ih_f;
    const float* __restrict__ b_hh = bwd ? b_hh_b : b_hh_f;
    float* __restrict__ P          = bwd ? Pb     : Pf;

    __shared__ float es[8][H];
    // cooperative load of 8 embedding rows (512 floats, 2 per thread)
    {
        int idx = j;
        #pragma unroll
        for (int rep = 0; rep < 2; ++rep, idx += 256) {
            int r = idx >> 6, col = idx & 63;
            int v = v0 + r;
            float val = 0.0f;
            if (v < V && v != 0) val = emb[v * H + col];   // padding_idx=0
            es[r][col] = val;
        }
    }

    float w[H];
    const float4* w4 = reinterpret_cast<const float4*>(w_ih + j * H);
    #pragma unroll
    for (int i = 0; i < 16; ++i) {
        float4 t = w4[i];
        w[4*i] = t.x; w[4*i+1] = t.y; w[4*i+2] = t.z; w[4*i+3] = t.w;
    }
    float bias = b_ih[j] + b_hh[j];
    __syncthreads();

    #pragma unroll
    for (int r = 0; r < 8; ++r) {
        int v = v0 + r;
        if (v >= V) break;
        float a0 = 0, a1 = 0, a2 = 0, a3 = 0;
        #pragma unroll
        for (int k = 0; k < H; k += 4) {
            a0 = fmaf(es[r][k+0], w[k+0], a0);
            a1 = fmaf(es[r][k+1], w[k+1], a1);
            a2 = fmaf(es[r][k+2], w[k+2], a2);
            a3 = fmaf(es[r][k+3], w[k+3], a3);
        }
        P[v * G4 + j] = bias + ((a0 + a1) + (a2 + a3));
    }
}

// One block per batch element. 4 waves; wave w owns gate w (rows 64w..64w+63
// of w_hh). Weights live in 16 NAMED float4 locals -- R1/R2/R3 evidence:
// `float w[64]` defeats SROA (array stays in scratch -> per-step reloads,
// VGPR_Count=40), and AGPR parking via volatile asm serializes the scheduler
// (R3: 1205us). Named float4s give 64 clean SSA values the allocator keeps
// in VGPRs under the 512-reg budget of __launch_bounds__(256,1).
__global__ __launch_bounds__(256, 1)
void lstm_kernel(const int* __restrict__ x,      // [B,T]
                 const float* __restrict__ Pf,   // [V,4H]
                 const float* __restrict__ Pb,   // [V,4H]
                 const float* __restrict__ w_hh, // [4H,H] (forward)
                 const float* __restrict__ w_fc, // [12,2H]
                 const float* __restrict__ b_fc, // [12]
                 float* __restrict__ out,        // [B,12]
                 int T)
{
    const int b    = blockIdx.x;
    const int j    = threadIdx.x;   // gate-output row 0..255
    const int lane = j & 63;
    const int gate = j >> 6;        // == wave id: 0=i 1=f 2=g 3=o

    // per-thread recurrent weight row: 16 named float4 (NOT an array)
    const float4* w4 = reinterpret_cast<const float4*>(w_hh + j * H);
    float4 q0  = w4[0],  q1  = w4[1],  q2  = w4[2],  q3  = w4[3];
    float4 q4  = w4[4],  q5  = w4[5],  q6  = w4[6],  q7  = w4[7];
    float4 q8  = w4[8],  q9  = w4[9],  q10 = w4[10], q11 = w4[11];
    float4 q12 = w4[12], q13 = w4[13], q14 = w4[14], q15 = w4[15];

    // branchless activation: act = Aa * sigm(ms*s) + Ba
    const float ms = (gate == 2) ? 2.0f : 1.0f;
    const float Aa = (gate == 2) ? 2.0f : 1.0f;
    const float Ba = (gate == 2) ? -1.0f : 0.0f;

    __shared__ float g_s[2][G4];
    __shared__ float hf_s[H];
    __shared__ float hb_s[H];

    const int* __restrict__ xrow = x + (long)b * T;

    float h = 0.0f;   // lane's h value (replicated across all 4 waves)
    float c = 0.0f;

    int   tok_next = (T > 1) ? xrow[1] : 0;
    float p_cur    = Pf[xrow[0] * G4 + j];

    for (int t = 0; t < T; ++t) {
        // prefetch next timestep's projected input (L2-resident gather)
        float p_next = 0.0f;
        if (t + 1 < T) p_next = Pf[tok_next * G4 + j];
        int tok_next2 = (t + 2 < T) ? xrow[t + 2] : 0;

        // s = p_cur + sum_k w[k] * h[k]   (h broadcast via readlane -> SGPR,
        // consumed directly as the fma's single SGPR operand)
        float a0 = 0, a1 = 0, a2 = 0, a3 = 0;
        #define STEP4(i)                                        \
            a0 = fmaf(q##i.x, bcast(h, 4*(i)+0), a0);           \
            a1 = fmaf(q##i.y, bcast(h, 4*(i)+1), a1);           \
            a2 = fmaf(q##i.z, bcast(h, 4*(i)+2), a2);           \
            a3 = fmaf(q##i.w, bcast(h, 4*(i)+3), a3);
        STEP4(0)  STEP4(1)  STEP4(2)  STEP4(3)
        STEP4(4)  STEP4(5)  STEP4(6)  STEP4(7)
        STEP4(8)  STEP4(9)  STEP4(10) STEP4(11)
        STEP4(12) STEP4(13) STEP4(14) STEP4(15)
        #undef STEP4

        float s   = p_cur + ((a0 + a1) + (a2 + a3));
        float act = fmaf(Aa, sigm(ms * s), Ba);

        const int ph = t & 1;
        g_s[ph][j] = act;
        __syncthreads();   // the single per-step barrier (gate exchange)

        float gi = g_s[ph][lane];
        float gf = g_s[ph][H   + lane];
        float gg = g_s[ph][2*H + lane];
        float go = g_s[ph][3*H + lane];
        c = fmaf(gf, c, gi * gg);
        h = go * tanh_s(c);

        p_cur    = p_next;
        tok_next = tok_next2;
    }

    __syncthreads();   // protect g_s[0] reuse below

    // backward LSTM: exactly one step (hs_b[0]) with zero initial state
    {
        int   tokL = xrow[T - 1];
        float gb   = Pb[tokL * G4 + j];
        g_s[0][j]  = fmaf(Aa, sigm(ms * gb), Ba);
    }
    if (gate == 0) hf_s[lane] = h;
    __syncthreads();

    if (j < H) {
        float i_ = g_s[0][j];
        float gg = g_s[0][2*H + j];
        float go = g_s[0][3*H + j];
        float cb = i_ * gg;               // f*c0 = 0
        hb_s[j] = go * tanh_s(cb);
    }
    __syncthreads();

    // final FC: y[b, j] = b_fc[j] + [h_f | h_b] . w_fc[j]
    if (j < 12) {
        float acc = b_fc[j];
        const float* wf = w_fc + j * (2 * H);
        #pragma unroll
        for (int k = 0; k < H; ++k) acc = fmaf(hf_s[k], wf[k], acc);
        #pragma unroll
        for (int k = 0; k < H; ++k) acc = fmaf(hb_s[k], wf[H + k], acc);
        out[b * 12 + j] = acc;
    }
}

extern "C" void kernel_launch(void* const* d_in, const int* in_sizes, int n_in,
                              void* d_out, int out_size, void* d_ws, size_t ws_size,
                              hipStream_t stream)
{
    const int*   x      = (const int*)  d_in[0];
    const float* emb    = (const float*)d_in[1];
    const float* w_ih_f = (const float*)d_in[2];
    const float* w_hh_f = (const float*)d_in[3];
    const float* b_ih_f = (const float*)d_in[4];
    const float* b_hh_f = (const float*)d_in[5];
    const float* w_ih_b = (const float*)d_in[6];
    // d_in[7] = w_hh_b (unused: backward runs exactly one step from zero state)
    const float* b_ih_b = (const float*)d_in[8];
    const float* b_hh_b = (const float*)d_in[9];
    const float* w_fc   = (const float*)d_in[10];
    const float* b_fc   = (const float*)d_in[11];
    float* out = (float*)d_out;

    const int B = out_size / 12;
    const int T = in_sizes[0] / B;
    const int V = in_sizes[1] / H;

    float* Pf = (float*)d_ws;                   // [V,4H]
    float* Pb = Pf + (size_t)V * G4;            // [V,4H]  (4 MB total)

    int pblocks = (V + 7) / 8;
    dim3 pgrid(pblocks, 2);
    proj_kernel<<<pgrid, 256, 0, stream>>>(emb, w_ih_f, b_ih_f, b_hh_f,
                                           w_ih_b, b_ih_b, b_hh_b, Pf, Pb, V);
    lstm_kernel<<<B, 256, 0, stream>>>(x, Pf, Pb, w_hh_f, w_fc, b_fc, out, T);
}

// Round 5
// 972.593 us; speedup vs baseline: 1.2697x; 1.0014x over previous
//
#include <hip/hip_runtime.h>

#define H  64
#define G4 256   // 4*H

// fast sigmoid/tanh: v_exp_f32 + v_rcp_f32. Safe at +-inf:
//   x->-inf: exp(-x)=inf -> rcp(inf)=0 ; x->+inf: exp(-x)=0 -> rcp(1)=1
__device__ __forceinline__ float sigm(float x) {
    return __builtin_amdgcn_rcpf(1.0f + __expf(-x));
}
__device__ __forceinline__ float tanh_s(float x) {
    return fmaf(2.0f, sigm(2.0f * x), -1.0f);
}

__device__ __forceinline__ float bcast(float v, int lane) {
    return __int_as_float(__builtin_amdgcn_readlane(__float_as_int(v), lane));
}

// P[v][g] = sum_h table[v][h] * w_ih[g][h] + b_ih[g] + b_hh[g], table[0] = 0
// blockIdx.y = 0 -> forward params, 1 -> backward params.
__global__ __launch_bounds__(256)
void proj_kernel(const float* __restrict__ emb,
                 const float* __restrict__ w_ih_f,
                 const float* __restrict__ b_ih_f,
                 const float* __restrict__ b_hh_f,
                 const float* __restrict__ w_ih_b,
                 const float* __restrict__ b_ih_b,
                 const float* __restrict__ b_hh_b,
                 float* __restrict__ Pf,
                 float* __restrict__ Pb,
                 int V)
{
    const int j  = threadIdx.x;       // output gate index 0..255
    const int v0 = blockIdx.x * 8;
    const bool bwd = (blockIdx.y != 0);

    const float* __restrict__ w_ih = bwd ? w_ih_b : w_ih_f;
    const float* __restrict__ b_ih = bwd ? b_ih_b : b_ih_f;
    const float* __restrict__ b_hh = bwd ? b_hh_b : b_hh_f;
    float* __restrict__ P          = bwd ? Pb     : Pf;

    __shared__ float es[8][H];
    // cooperative load of 8 embedding rows (512 floats, 2 per thread)
    {
        int idx = j;
        #pragma unroll
        for (int rep = 0; rep < 2; ++rep, idx += 256) {
            int r = idx >> 6, col = idx & 63;
            int v = v0 + r;
            float val = 0.0f;
            if (v < V && v != 0) val = emb[v * H + col];   // padding_idx=0
            es[r][col] = val;
        }
    }

    float w[H];
    const float4* w4 = reinterpret_cast<const float4*>(w_ih + j * H);
    #pragma unroll
    for (int i = 0; i < 16; ++i) {
        float4 t = w4[i];
        w[4*i] = t.x; w[4*i+1] = t.y; w[4*i+2] = t.z; w[4*i+3] = t.w;
    }
    float bias = b_ih[j] + b_hh[j];
    __syncthreads();

    #pragma unroll
    for (int r = 0; r < 8; ++r) {
        int v = v0 + r;
        if (v >= V) break;
        float a0 = 0, a1 = 0, a2 = 0, a3 = 0;
        #pragma unroll
        for (int k = 0; k < H; k += 4) {
            a0 = fmaf(es[r][k+0], w[k+0], a0);
            a1 = fmaf(es[r][k+1], w[k+1], a1);
            a2 = fmaf(es[r][k+2], w[k+2], a2);
            a3 = fmaf(es[r][k+3], w[k+3], a3);
        }
        P[v * G4 + j] = bias + ((a0 + a1) + (a2 + a3));
    }
}

// One block per batch element. 4 waves; wave w owns gate w (rows 64w..64w+63
// of w_hh) held in VGPRs as 64 NAMED scalars, each pinned ONCE (pre-loop) by
// an empty volatile asm. Evidence trail: R1/R2/R4 all show VGPR_Count=40 --
// the AMDGPU RA treats const-__restrict__ loads as invariant/rematerializable
// and re-executes the 16 dwordx4 loads EVERY step (64KB/step L2 refetch =
// 1117 cyc/step measured). R3 proved residency is possible (AGPR, 116 VGPR)
// but per-step volatile asm serialized the loop (1205us). The pre-loop pin
// makes the values opaque asm results (non-rematerializable) at zero
// per-step cost.
__global__ __launch_bounds__(256, 1)
void lstm_kernel(const int* __restrict__ x,      // [B,T]
                 const float* __restrict__ Pf,   // [V,4H]
                 const float* __restrict__ Pb,   // [V,4H]
                 const float* __restrict__ w_hh, // [4H,H] (forward)
                 const float* __restrict__ w_fc, // [12,2H]
                 const float* __restrict__ b_fc, // [12]
                 float* __restrict__ out,        // [B,12]
                 int T)
{
    const int b    = blockIdx.x;
    const int j    = threadIdx.x;   // gate-output row 0..255
    const int lane = j & 63;
    const int gate = j >> 6;        // == wave id: 0=i 1=f 2=g 3=o

    // per-thread recurrent weight row -> 64 named scalars, pinned pre-loop
    const float4* w4 = reinterpret_cast<const float4*>(w_hh + j * H);
    #define QLOAD(i)                                                          \
        float4 t##i = w4[i];                                                  \
        float w##i##x = t##i.x, w##i##y = t##i.y,                             \
              w##i##z = t##i.z, w##i##w = t##i.w;                             \
        asm volatile("" : "+v"(w##i##x), "+v"(w##i##y),                       \
                          "+v"(w##i##z), "+v"(w##i##w));
    QLOAD(0)  QLOAD(1)  QLOAD(2)  QLOAD(3)
    QLOAD(4)  QLOAD(5)  QLOAD(6)  QLOAD(7)
    QLOAD(8)  QLOAD(9)  QLOAD(10) QLOAD(11)
    QLOAD(12) QLOAD(13) QLOAD(14) QLOAD(15)
    #undef QLOAD

    // branchless activation: act = Aa * sigm(ms*s) + Ba
    const float ms = (gate == 2) ? 2.0f : 1.0f;
    const float Aa = (gate == 2) ? 2.0f : 1.0f;
    const float Ba = (gate == 2) ? -1.0f : 0.0f;

    __shared__ float g_s[2][G4];
    __shared__ float hf_s[H];
    __shared__ float hb_s[H];

    const int* __restrict__ xrow = x + (long)b * T;

    float h = 0.0f;   // lane's h value (replicated across all 4 waves)
    float c = 0.0f;

    int   tok_next = (T > 1) ? xrow[1] : 0;
    float p_cur    = Pf[xrow[0] * G4 + j];

    for (int t = 0; t < T; ++t) {
        // prefetch next timestep's projected input (L2-resident gather)
        float p_next = 0.0f;
        if (t + 1 < T) p_next = Pf[tok_next * G4 + j];
        int tok_next2 = (t + 2 < T) ? xrow[t + 2] : 0;

        // s = p_cur + sum_k w[k] * h[k]   (h broadcast via readlane -> SGPR,
        // consumed directly as the fma's single SGPR operand)
        float a0 = 0, a1 = 0, a2 = 0, a3 = 0;
        #define STEP4(i)                                        \
            a0 = fmaf(w##i##x, bcast(h, 4*(i)+0), a0);          \
            a1 = fmaf(w##i##y, bcast(h, 4*(i)+1), a1);          \
            a2 = fmaf(w##i##z, bcast(h, 4*(i)+2), a2);          \
            a3 = fmaf(w##i##w, bcast(h, 4*(i)+3), a3);
        STEP4(0)  STEP4(1)  STEP4(2)  STEP4(3)
        STEP4(4)  STEP4(5)  STEP4(6)  STEP4(7)
        STEP4(8)  STEP4(9)  STEP4(10) STEP4(11)
        STEP4(12) STEP4(13) STEP4(14) STEP4(15)
        #undef STEP4

        float s   = p_cur + ((a0 + a1) + (a2 + a3));
        float act = fmaf(Aa, sigm(ms * s), Ba);

        const int ph = t & 1;
        g_s[ph][j] = act;
        __syncthreads();   // the single per-step barrier (gate exchange)

        float gi = g_s[ph][lane];
        float gf = g_s[ph][H   + lane];
        float gg = g_s[ph][2*H + lane];
        float go = g_s[ph][3*H + lane];
        c = fmaf(gf, c, gi * gg);
        h = go * tanh_s(c);

        p_cur    = p_next;
        tok_next = tok_next2;
    }

    __syncthreads();   // protect g_s[0] reuse below

    // backward LSTM: exactly one step (hs_b[0]) with zero initial state
    {
        int   tokL = xrow[T - 1];
        float gb   = Pb[tokL * G4 + j];
        g_s[0][j]  = fmaf(Aa, sigm(ms * gb), Ba);
    }
    if (gate == 0) hf_s[lane] = h;
    __syncthreads();

    if (j < H) {
        float i_ = g_s[0][j];
        float gg = g_s[0][2*H + j];
        float go = g_s[0][3*H + j];
        float cb = i_ * gg;               // f*c0 = 0
        hb_s[j] = go * tanh_s(cb);
    }
    __syncthreads();

    // final FC: y[b, j] = b_fc[j] + [h_f | h_b] . w_fc[j]
    if (j < 12) {
        float acc = b_fc[j];
        const float* wf = w_fc + j * (2 * H);
        #pragma unroll
        for (int k = 0; k < H; ++k) acc = fmaf(hf_s[k], wf[k], acc);
        #pragma unroll
        for (int k = 0; k < H; ++k) acc = fmaf(hb_s[k], wf[H + k], acc);
        out[b * 12 + j] = acc;
    }
}

extern "C" void kernel_launch(void* const* d_in, const int* in_sizes, int n_in,
                              void* d_out, int out_size, void* d_ws, size_t ws_size,
                              hipStream_t stream)
{
    const int*   x      = (const int*)  d_in[0];
    const float* emb    = (const float*)d_in[1];
    const float* w_ih_f = (const float*)d_in[2];
    const float* w_hh_f = (const float*)d_in[3];
    const float* b_ih_f = (const float*)d_in[4];
    const float* b_hh_f = (const float*)d_in[5];
    const float* w_ih_b = (const float*)d_in[6];
    // d_in[7] = w_hh_b (unused: backward runs exactly one step from zero state)
    const float* b_ih_b = (const float*)d_in[8];
    const float* b_hh_b = (const float*)d_in[9];
    const float* w_fc   = (const float*)d_in[10];
    const float* b_fc   = (const float*)d_in[11];
    float* out = (float*)d_out;

    const int B = out_size / 12;
    const int T = in_sizes[0] / B;
    const int V = in_sizes[1] / H;

    float* Pf = (float*)d_ws;                   // [V,4H]
    float* Pb = Pf + (size_t)V * G4;            // [V,4H]  (4 MB total)

    int pblocks = (V + 7) / 8;
    dim3 pgrid(pblocks, 2);
    proj_kernel<<<pgrid, 256, 0, stream>>>(emb, w_ih_f, b_ih_f, b_hh_f,
                                           w_ih_b, b_ih_b, b_hh_b, Pf, Pb, V);
    lstm_kernel<<<B, 256, 0, stream>>>(x, Pf, Pb, w_hh_f, w_fc, b_fc, out, T);
}